// Round 7
// baseline (327.729 us; speedup 1.0000x reference)
//
#include <hip/hip_runtime.h>

#define BB 16
#define KD 128
#define ND 8000
#define DD 256
#define LMB 1000.0f

typedef __attribute__((ext_vector_type(8))) short bf16x8;
typedef __attribute__((ext_vector_type(4))) short bf16x4;
typedef __attribute__((ext_vector_type(4))) float f32x4;
typedef unsigned short ushort_t;

// exact split: x = hi + lo (hi = truncate-to-bf16, lo = RNE(x - hi))
__device__ inline void split_bf16(float x, ushort_t& h, ushort_t& l) {
    unsigned int bi = __float_as_uint(x);
    h = (ushort_t)(bi >> 16);
    float lo = x - __uint_as_float(bi & 0xFFFF0000u);
    unsigned int lb = __float_as_uint(lo);
    lb = lb + 0x7FFFu + ((lb >> 16) & 1u);
    l = (ushort_t)(lb >> 16);
}

// ---------------- K1: projection  sd[b][k][d] = sum_n pinv[b][k][n]*descr[b][d][n]
// Split-bf16 MFMA (a*b ~= ah*bh + ah*bl + al*bh). grid (16,2,16) = 512 blocks
// (2/CU), 512 thr = 8 waves. 500 n per block = 15 chunks of 32 + tail 20.
// Software pipeline: issue next-chunk global loads before MFMA phase (T14).
#define PSTR 40
#define NPS 500
#define NCHK 16

__global__ __launch_bounds__(512, 4) void proj_kernel(
    const float* __restrict__ pinv_a, const float* __restrict__ descr_a,
    const float* __restrict__ pinv_b, const float* __restrict__ descr_b,
    float* __restrict__ sd_a, float* __restrict__ sd_b)
{
    const int b = blockIdx.x, which = blockIdx.y, slice = blockIdx.z;
    const float* P  = (which ? pinv_b  : pinv_a)  + (size_t)b * KD * ND;
    const float* Dm = (which ? descr_b : descr_a) + (size_t)b * DD * ND;
    float* outp = (which ? sd_b : sd_a) + (size_t)b * KD * DD;

    __shared__ ushort_t Ph[KD][PSTR], Pl[KD][PSTR];
    __shared__ ushort_t Dh[DD][PSTR], Dl[DD][PSTR];

    const int tid = threadIdx.x;
    const int lane = tid & 63;
    const int wid = tid >> 6;
    const int wm = wid >> 2, wn = wid & 3;
    const int fr = lane & 15;
    const int kg = lane >> 4;
    const int n0 = slice * NPS;

    // per-thread staging coordinates (u=0: P, u=1,2: D)
    int srow[3], sg[3];
    const float* sptr[3];
    {
        srow[0] = tid >> 2; sg[0] = tid & 3;
        sptr[0] = P + (size_t)srow[0] * ND + n0 + sg[0] * 8;
        int s1 = tid;       srow[1] = s1 >> 2; sg[1] = s1 & 3;
        sptr[1] = Dm + (size_t)srow[1] * ND + n0 + sg[1] * 8;
        int s2 = tid + 512; srow[2] = s2 >> 2; sg[2] = s2 & 3;
        sptr[2] = Dm + (size_t)srow[2] * ND + n0 + sg[2] * 8;
    }

    f32x4 acc[4][4];
    #pragma unroll
    for (int i = 0; i < 4; ++i)
        #pragma unroll
        for (int j = 0; j < 4; ++j) acc[i][j] = (f32x4){0.f, 0.f, 0.f, 0.f};

    float4 pv0, pv1, pv2, pv3, pv4, pv5;

    // issue loads for chunk 0
    {
        const int nb = 0, valid = 32;
        pv0 = (sg[0] * 8     < valid) ? *(const float4*)(sptr[0] + nb)     : (float4){0,0,0,0};
        pv1 = (sg[0] * 8 + 4 < valid) ? *(const float4*)(sptr[0] + nb + 4) : (float4){0,0,0,0};
        pv2 = (sg[1] * 8     < valid) ? *(const float4*)(sptr[1] + nb)     : (float4){0,0,0,0};
        pv3 = (sg[1] * 8 + 4 < valid) ? *(const float4*)(sptr[1] + nb + 4) : (float4){0,0,0,0};
        pv4 = (sg[2] * 8     < valid) ? *(const float4*)(sptr[2] + nb)     : (float4){0,0,0,0};
        pv5 = (sg[2] * 8 + 4 < valid) ? *(const float4*)(sptr[2] + nb + 4) : (float4){0,0,0,0};
    }

    for (int ch = 0; ch < NCHK; ++ch) {
        // ---- commit: convert prefetched regs -> LDS
        #pragma unroll
        for (int u = 0; u < 3; ++u) {
            float4 a = (u == 0) ? pv0 : (u == 1) ? pv2 : pv4;
            float4 c = (u == 0) ? pv1 : (u == 1) ? pv3 : pv5;
            float xs[8] = {a.x, a.y, a.z, a.w, c.x, c.y, c.z, c.w};
            bf16x8 hvec, lvec;
            #pragma unroll
            for (int j = 0; j < 8; ++j) {
                ushort_t hh, ll;
                split_bf16(xs[j], hh, ll);
                hvec[j] = (short)hh; lvec[j] = (short)ll;
            }
            ushort_t* dh = (u == 0) ? &Ph[srow[0]][sg[0] * 8] : &Dh[srow[u]][sg[u] * 8];
            ushort_t* dl = (u == 0) ? &Pl[srow[0]][sg[0] * 8] : &Dl[srow[u]][sg[u] * 8];
            *(bf16x8*)dh = hvec;
            *(bf16x8*)dl = lvec;
        }
        __syncthreads();

        // ---- issue loads for chunk ch+1 (in flight during MFMA below)
        if (ch + 1 < NCHK) {
            const int nb = (ch + 1) * 32;
            const int valid = (ch + 1 == NCHK - 1) ? (NPS - 32 * (NCHK - 1)) : 32;
            pv0 = (sg[0] * 8     < valid) ? *(const float4*)(sptr[0] + nb)     : (float4){0,0,0,0};
            pv1 = (sg[0] * 8 + 4 < valid) ? *(const float4*)(sptr[0] + nb + 4) : (float4){0,0,0,0};
            pv2 = (sg[1] * 8     < valid) ? *(const float4*)(sptr[1] + nb)     : (float4){0,0,0,0};
            pv3 = (sg[1] * 8 + 4 < valid) ? *(const float4*)(sptr[1] + nb + 4) : (float4){0,0,0,0};
            pv4 = (sg[2] * 8     < valid) ? *(const float4*)(sptr[2] + nb)     : (float4){0,0,0,0};
            pv5 = (sg[2] * 8 + 4 < valid) ? *(const float4*)(sptr[2] + nb + 4) : (float4){0,0,0,0};
        }

        // ---- MFMA over this K=32 chunk
        bf16x8 Ah[4], Al[4];
        #pragma unroll
        for (int mi = 0; mi < 4; ++mi) {
            int r = wm * 64 + mi * 16 + fr;
            Ah[mi] = *(const bf16x8*)&Ph[r][kg * 8];
            Al[mi] = *(const bf16x8*)&Pl[r][kg * 8];
        }
        #pragma unroll
        for (int ni = 0; ni < 4; ++ni) {
            int c = wn * 64 + ni * 16 + fr;
            bf16x8 Bh = *(const bf16x8*)&Dh[c][kg * 8];
            bf16x8 Bl = *(const bf16x8*)&Dl[c][kg * 8];
            #pragma unroll
            for (int mi = 0; mi < 4; ++mi) {
                acc[mi][ni] = __builtin_amdgcn_mfma_f32_16x16x32_bf16(Ah[mi], Bh, acc[mi][ni], 0, 0, 0);
                acc[mi][ni] = __builtin_amdgcn_mfma_f32_16x16x32_bf16(Ah[mi], Bl, acc[mi][ni], 0, 0, 0);
                acc[mi][ni] = __builtin_amdgcn_mfma_f32_16x16x32_bf16(Al[mi], Bh, acc[mi][ni], 0, 0, 0);
            }
        }
        __syncthreads();
    }

    #pragma unroll
    for (int mi = 0; mi < 4; ++mi)
        #pragma unroll
        for (int ni = 0; ni < 4; ++ni) {
            int rbase = wm * 64 + mi * 16 + kg * 4;
            int ccol  = wn * 64 + ni * 16 + fr;
            #pragma unroll
            for (int r = 0; r < 4; ++r)
                atomicAdd(&outp[(size_t)(rbase + r) * DD + ccol], acc[mi][ni][r]);
        }
}

// ---------------- K2: masks (lambda folded in)
__global__ __launch_bounds__(256) void mask_kernel(
    const float* __restrict__ ea_g, const float* __restrict__ eb_g,
    float* __restrict__ lm_ab, float* __restrict__ lm_ba)
{
    const int b = blockIdx.x, tid = threadIdx.x;
    __shared__ float ta[KD], ua[KD], tb[KD], ub[KD];
    __shared__ float red[256];
    float e = (tid < KD) ? ea_g[b * KD + tid] : eb_g[b * KD + (tid - KD)];
    red[tid] = e;
    __syncthreads();
    for (int s = 128; s > 0; s >>= 1) {
        if (tid < s) red[tid] = fmaxf(red[tid], red[tid + s]);
        __syncthreads();
    }
    float is = 1.0f / red[0];
    float g = e * is;
    float den = 1.0f / (g * g + 1.0f);
    if (tid < KD) { ta[tid] = g * den; ua[tid] = den; }
    else          { tb[tid - KD] = g * den; ub[tid - KD] = den; }
    __syncthreads();
    for (int idx = tid; idx < KD * KD; idx += 256) {
        int i = idx >> 7, kc = idx & 127;
        float re = tb[i] - ta[kc], im = ub[i] - ua[kc];
        lm_ab[(size_t)b * KD * KD + idx] = LMB * (re * re + im * im);
        float re2 = ta[i] - tb[kc], im2 = ua[i] - ub[kc];
        lm_ba[(size_t)b * KD * KD + idx] = LMB * (re2 * re2 + im2 * im2);
    }
}

// ---------------- K3: Grams via split-bf16 MFMA, d-split for parallelism.
// grid (16, 3 m, 4 dchunk) = 192 blocks; each block one 64-wide d-chunk,
// atomicAdd into zeroed AA. m=0: (Sa,Sa) m=1: (Sb,Sb) m=2: (Sb,Sa).
#define GSTR 68
__global__ __launch_bounds__(512, 2) void gram_kernel(
    const float* __restrict__ sd_a, const float* __restrict__ sd_b,
    float* __restrict__ AA)
{
    const int b = blockIdx.x, m = blockIdx.y, dchunk = blockIdx.z;
    const float* X = (m == 0) ? sd_a : sd_b;
    const float* Y = (m == 2) ? sd_a : X;
    X += (size_t)b * KD * DD;
    Y += (size_t)b * KD * DD;
    float* outp = AA + ((size_t)m * BB + b) * KD * KD;
    const int d0 = dchunk * 64;

    __shared__ ushort_t Xh[KD][GSTR], Xl[KD][GSTR];
    __shared__ ushort_t Yh[KD][GSTR], Yl[KD][GSTR];

    const int tid = threadIdx.x;
    const int lane = tid & 63;
    const int wid = tid >> 6;
    const int wm = wid >> 2, wn = wid & 3;
    const int fr = lane & 15;
    const int kg = lane >> 4;

    f32x4 acc[4][2];
    #pragma unroll
    for (int i = 0; i < 4; ++i)
        #pragma unroll
        for (int j = 0; j < 2; ++j) acc[i][j] = (f32x4){0.f, 0.f, 0.f, 0.f};

    #pragma unroll
    for (int u = 0; u < 8; ++u) {
        int idx = tid + (u & 3) * 512;
        int r = idx >> 4, c4 = idx & 15;
        const float* src = (u < 4) ? X : Y;
        float4 v = *(const float4*)(src + (size_t)r * DD + d0 + c4 * 4);
        float xs[4] = {v.x, v.y, v.z, v.w};
        bf16x4 hv, lv;
        #pragma unroll
        for (int q = 0; q < 4; ++q) {
            ushort_t hh, ll;
            split_bf16(xs[q], hh, ll);
            hv[q] = (short)hh; lv[q] = (short)ll;
        }
        if (u < 4) {
            *(bf16x4*)&Xh[r][c4 * 4] = hv;
            *(bf16x4*)&Xl[r][c4 * 4] = lv;
        } else {
            *(bf16x4*)&Yh[r][c4 * 4] = hv;
            *(bf16x4*)&Yl[r][c4 * 4] = lv;
        }
    }
    __syncthreads();

    #pragma unroll
    for (int kk = 0; kk < 2; ++kk) {
        const int co = kk * 32 + kg * 8;
        bf16x8 Ah[4], Al[4];
        #pragma unroll
        for (int mi = 0; mi < 4; ++mi) {
            int r = wm * 64 + mi * 16 + fr;
            Ah[mi] = *(const bf16x8*)&Xh[r][co];
            Al[mi] = *(const bf16x8*)&Xl[r][co];
        }
        #pragma unroll
        for (int ni = 0; ni < 2; ++ni) {
            int c = wn * 32 + ni * 16 + fr;
            bf16x8 Bh = *(const bf16x8*)&Yh[c][co];
            bf16x8 Bl = *(const bf16x8*)&Yl[c][co];
            #pragma unroll
            for (int mi = 0; mi < 4; ++mi) {
                acc[mi][ni] = __builtin_amdgcn_mfma_f32_16x16x32_bf16(Ah[mi], Bh, acc[mi][ni], 0, 0, 0);
                acc[mi][ni] = __builtin_amdgcn_mfma_f32_16x16x32_bf16(Ah[mi], Bl, acc[mi][ni], 0, 0, 0);
                acc[mi][ni] = __builtin_amdgcn_mfma_f32_16x16x32_bf16(Al[mi], Bh, acc[mi][ni], 0, 0, 0);
            }
        }
    }

    #pragma unroll
    for (int mi = 0; mi < 4; ++mi)
        #pragma unroll
        for (int ni = 0; ni < 2; ++ni) {
            int rbase = wm * 64 + mi * 16 + kg * 4;
            int ccol  = wn * 32 + ni * 16 + fr;
            #pragma unroll
            for (int rr = 0; rr < 4; ++rr)
                atomicAdd(&outp[(size_t)(rbase + rr) * KD + ccol], acc[mi][ni][rr]);
        }
}

// ---------------- K4: register-resident Gauss-Jordan inversion (SPD, no pivoting).
__global__ __launch_bounds__(512, 2) void invert_kernel(
    const float* __restrict__ AA, float* __restrict__ Hout)
{
    const int b = blockIdx.x, which = blockIdx.y;
    const float* src = AA + ((size_t)which * BB + b) * KD * KD;
    float* dst = Hout + ((size_t)which * BB + b) * KD * KD;

    __shared__ float rowbuf[2][KD];
    __shared__ float colbuf[2][KD];

    const int tid = threadIdx.x;
    const int rb = tid >> 5;
    const int cg = tid & 31;

    f32x4 Areg[8];
    #pragma unroll
    for (int r = 0; r < 8; ++r)
        Areg[r] = *(const f32x4*)(src + (size_t)(rb * 8 + r) * KD + cg * 4);

    if (rb == 0) *(f32x4*)&rowbuf[0][cg * 4] = Areg[0];
    if (cg == 0) {
        #pragma unroll
        for (int r = 0; r < 8; ++r) colbuf[0][rb * 8 + r] = Areg[r].x;
    }
    __syncthreads();

    for (int j = 0; j < KD; ++j) {
        const int cur = j & 1, nxt = cur ^ 1;
        const int jrb = j >> 3, jr = j & 7, jcg = j >> 2, jc = j & 3;
        const float pv = 1.0f / rowbuf[cur][j];
        const f32x4 orow = *(const f32x4*)&rowbuf[cur][cg * 4];
        const f32x4 prow = orow * pv;
        const bool mycg = (cg == jcg);
        const bool myrb = (rb == jrb);

        #pragma unroll
        for (int r = 0; r < 8; ++r) {
            const float cm = colbuf[cur][rb * 8 + r];
            const float cmul = -cm * pv;
            const bool piv = myrb && (r == jr);
            f32x4 nv;
            nv.x = piv ? prow.x : fmaf(cmul, orow.x, Areg[r].x);
            nv.y = piv ? prow.y : fmaf(cmul, orow.y, Areg[r].y);
            nv.z = piv ? prow.z : fmaf(cmul, orow.z, Areg[r].z);
            nv.w = piv ? prow.w : fmaf(cmul, orow.w, Areg[r].w);
            if (mycg) {
                const float fixv = piv ? pv : cmul;
                nv.x = (jc == 0) ? fixv : nv.x;
                nv.y = (jc == 1) ? fixv : nv.y;
                nv.z = (jc == 2) ? fixv : nv.z;
                nv.w = (jc == 3) ? fixv : nv.w;
            }
            Areg[r] = nv;
        }

        if (j + 1 < KD) {
            const int njrb = (j + 1) >> 3, njr = (j + 1) & 7;
            const int njcg = (j + 1) >> 2, njc = (j + 1) & 3;
            if (rb == njrb) {
                #pragma unroll
                for (int r = 0; r < 8; ++r)
                    if (r == njr) *(f32x4*)&rowbuf[nxt][cg * 4] = Areg[r];
            }
            if (cg == njcg) {
                #pragma unroll
                for (int r = 0; r < 8; ++r) {
                    const f32x4 a = Areg[r];
                    const float e = (njc == 0) ? a.x : (njc == 1) ? a.y : (njc == 2) ? a.z : a.w;
                    colbuf[nxt][rb * 8 + r] = e;
                }
            }
        }
        __syncthreads();
    }

    #pragma unroll
    for (int r = 0; r < 8; ++r)
        *(f32x4*)(dst + (size_t)(rb * 8 + r) * KD + cg * 4) = Areg[r];
}

// ---------------- K5: Neumann-series solve.
#define NTERMS 6
__global__ __launch_bounds__(512) void solve_kernel(
    const float* __restrict__ AAba, const float* __restrict__ lm_ab,
    const float* __restrict__ lm_ba, const float* __restrict__ Hmat,
    float* __restrict__ outp)
{
    const int b = blockIdx.x, cg = blockIdx.y, which = blockIdx.z;
    const float* Hm = Hmat + ((size_t)which * BB + b) * KD * KD;
    const float* lm = (which ? lm_ba : lm_ab) + (size_t)b * KD * KD;
    const float* Rs = AAba + (size_t)b * KD * KD;
    float* op = outp + ((size_t)which * BB + b) * KD * KD;
    const int i0 = cg * 32;

    __shared__ float Hs[KD][132];
    __shared__ float Zc[2][32][132];
    __shared__ float lms[32][132];

    const int tid = threadIdx.x;
    const int rq = tid & 31;
    const int cq = tid >> 5;

    #pragma unroll
    for (int u = 0; u < 8; ++u) {
        int idx = tid + u * 512;
        int d = idx >> 5, l4 = idx & 31;
        *(float4*)&Hs[d][l4 * 4] = *(const float4*)(Hm + (size_t)d * KD + l4 * 4);
    }
    #pragma unroll
    for (int u = 0; u < 8; ++u) {
        int idx = tid + u * 512;
        int ic = idx >> 7, l = idx & 127;
        lms[ic][l] = lm[(size_t)(i0 + ic) * KD + l];
    }
    if (which == 0) {
        #pragma unroll
        for (int u = 0; u < 8; ++u) {
            int idx = tid + u * 512;
            int ic = idx >> 7, d = idx & 127;
            Zc[0][ic][d] = Rs[(size_t)(i0 + ic) * KD + d];
        }
    } else {
        #pragma unroll
        for (int u = 0; u < 8; ++u) {
            int idx = tid + u * 512;
            int d = idx >> 5, ic = idx & 31;
            Zc[0][ic][d] = Rs[(size_t)d * KD + i0 + ic];
        }
    }
    __syncthreads();

    float xacc[4][2];
    #pragma unroll
    for (int rr = 0; rr < 4; ++rr) { xacc[rr][0] = 0.f; xacc[rr][1] = 0.f; }
    int cur = 0;
    for (int t = 0; t < NTERMS; ++t) {
        float zr[4][2];
        #pragma unroll
        for (int rr = 0; rr < 4; ++rr) { zr[rr][0] = 0.f; zr[rr][1] = 0.f; }
        #pragma unroll 8
        for (int d4 = 0; d4 < 32; ++d4) {
            float4 hv[4];
            #pragma unroll
            for (int dd = 0; dd < 4; ++dd)
                hv[dd] = *(const float4*)&Hs[d4 * 4 + dd][rq * 4];
            float4 wv[2];
            #pragma unroll
            for (int cc = 0; cc < 2; ++cc)
                wv[cc] = *(const float4*)&Zc[cur][cq * 2 + cc][d4 * 4];
            #pragma unroll
            for (int cc = 0; cc < 2; ++cc) {
                zr[0][cc] += hv[0].x * wv[cc].x + hv[1].x * wv[cc].y + hv[2].x * wv[cc].z + hv[3].x * wv[cc].w;
                zr[1][cc] += hv[0].y * wv[cc].x + hv[1].y * wv[cc].y + hv[2].y * wv[cc].z + hv[3].y * wv[cc].w;
                zr[2][cc] += hv[0].z * wv[cc].x + hv[1].z * wv[cc].y + hv[2].z * wv[cc].z + hv[3].z * wv[cc].w;
                zr[3][cc] += hv[0].w * wv[cc].x + hv[1].w * wv[cc].y + hv[2].w * wv[cc].z + hv[3].w * wv[cc].w;
            }
        }
        const float s = (t & 1) ? -1.f : 1.f;
        #pragma unroll
        for (int rr = 0; rr < 4; ++rr) {
            xacc[rr][0] += s * zr[rr][0];
            xacc[rr][1] += s * zr[rr][1];
        }
        if (t + 1 < NTERMS) {
            #pragma unroll
            for (int cc = 0; cc < 2; ++cc) {
                float4 lmv = *(const float4*)&lms[cq * 2 + cc][rq * 4];
                float4 w;
                w.x = lmv.x * zr[0][cc];
                w.y = lmv.y * zr[1][cc];
                w.z = lmv.z * zr[2][cc];
                w.w = lmv.w * zr[3][cc];
                *(float4*)&Zc[cur ^ 1][cq * 2 + cc][rq * 4] = w;
            }
            __syncthreads();
            cur ^= 1;
        }
    }
    #pragma unroll
    for (int cc = 0; cc < 2; ++cc) {
        float4 o;
        o.x = xacc[0][cc]; o.y = xacc[1][cc]; o.z = xacc[2][cc]; o.w = xacc[3][cc];
        *(float4*)(op + (size_t)(i0 + cq * 2 + cc) * KD + rq * 4) = o;
    }
}

extern "C" void kernel_launch(void* const* d_in, const int* in_sizes, int n_in,
                              void* d_out, int out_size, void* d_ws, size_t ws_size,
                              hipStream_t stream) {
    (void)in_sizes; (void)n_in; (void)out_size; (void)ws_size;
    const float* evals_a = (const float*)d_in[0];
    const float* pinv_a  = (const float*)d_in[1];
    const float* descr_a = (const float*)d_in[2];
    const float* evals_b = (const float*)d_in[3];
    const float* pinv_b  = (const float*)d_in[4];
    const float* descr_b = (const float*)d_in[5];
    float* out = (float*)d_out;
    float* ws = (float*)d_ws;

    const size_t SD = (size_t)BB * KD * DD;   // 524288
    const size_t MM = (size_t)BB * KD * KD;   // 262144
    float* sd_a  = ws;
    float* sd_b  = sd_a + SD;
    float* AA    = sd_b + SD;        // 3*MM: [0]=AA_aa [1]=AA_bb [2]=AA_ba
    float* lm_ab = AA + 3 * MM;
    float* lm_ba = lm_ab + MM;
    float* Hm    = lm_ba + MM;       // 2*MM

    // zero sd (proj atomics) and AA (gram atomics)
    hipMemsetAsync(sd_a, 0, (2 * SD + 3 * MM) * sizeof(float), stream);
    proj_kernel<<<dim3(BB, 2, 16), 512, 0, stream>>>(pinv_a, descr_a, pinv_b, descr_b, sd_a, sd_b);
    mask_kernel<<<dim3(BB), 256, 0, stream>>>(evals_a, evals_b, lm_ab, lm_ba);
    gram_kernel<<<dim3(BB, 3, 4), 512, 0, stream>>>(sd_a, sd_b, AA);
    invert_kernel<<<dim3(BB, 2), 512, 0, stream>>>(AA, Hm);
    solve_kernel<<<dim3(BB, 4, 2), 512, 0, stream>>>(AA + 2 * MM, lm_ab, lm_ba, Hm, out);
}